// Round 2
// baseline (392.391 us; speedup 1.0000x reference)
//
#include <hip/hip_runtime.h>
#include <math.h>

#define TPB  256
#define KC   64
#define WS   68              // LDS row stride (words) for W chunk
#define TOKS 16
#define H    2048
#define NE   64
#define NCH  (H / KC)        // 32 chunks
#define TAU  4.0e-3f         // rank-safety margin (fp32 vs ref divergence ~2e-5)
#define NEGF (-3.0e38f)

// ---------------- Pass 1: fp32 logits + top-3 + flag close calls ------------
__global__ __launch_bounds__(TPB) void moe_gate_fp32(
    const float* __restrict__ x,   // [T, H]
    const float* __restrict__ w,   // [NE, H]
    float* __restrict__ out,       // [2T idx floats][2T weight floats]
    int woff,
    unsigned char* __restrict__ flags)  // [T]
{
    __shared__ float Wl[NE * WS];      // 17408 B
    __shared__ float Xl[TOKS * KC];    // 4096 B

    const int tid = threadIdx.x;
    const int e   = tid & 63;          // expert = lane
    const int g   = tid >> 6;          // wave 0..3
    const int t0  = blockIdx.x * TOKS;

    // staging map: W chunk = 64 rows x 16 float4; X chunk = 16 rows x 16 float4
    const int wr0 = tid >> 4;          // 0..15
    const int wc4 = (tid & 15) * 4;    // float col 0,4,..,60
    const int xr  = tid >> 4;          // token row 0..15

    // prologue: prefetch chunk 0 into registers
    float4 wb[4], xb;
    #pragma unroll
    for (int i = 0; i < 4; ++i)
        wb[i] = *reinterpret_cast<const float4*>(&w[(size_t)(i * 16 + wr0) * H + wc4]);
    xb = *reinterpret_cast<const float4*>(&x[(size_t)(t0 + xr) * H + wc4]);

    float acc[4] = {0.f, 0.f, 0.f, 0.f};
    const int g4 = g * 4;

    for (int c = 0; c < NCH; ++c) {
        __syncthreads();               // previous chunk's compute done
        #pragma unroll
        for (int i = 0; i < 4; ++i)
            *reinterpret_cast<float4*>(&Wl[(i * 16 + wr0) * WS + wc4]) = wb[i];
        *reinterpret_cast<float4*>(&Xl[xr * KC + wc4]) = xb;
        __syncthreads();

        if (c + 1 < NCH) {             // prefetch next chunk (overlaps compute)
            const int kc = (c + 1) * KC;
            #pragma unroll
            for (int i = 0; i < 4; ++i)
                wb[i] = *reinterpret_cast<const float4*>(
                    &w[(size_t)(i * 16 + wr0) * H + kc + wc4]);
            xb = *reinterpret_cast<const float4*>(
                &x[(size_t)(t0 + xr) * H + kc + wc4]);
        }

        const float* wrp = &Wl[e * WS];
        const float* x0p = &Xl[(g4 + 0) * KC];
        const float* x1p = &Xl[(g4 + 1) * KC];
        const float* x2p = &Xl[(g4 + 2) * KC];
        const float* x3p = &Xl[(g4 + 3) * KC];

        #pragma unroll
        for (int k = 0; k < KC; k += 4) {
            const float4 wq = *reinterpret_cast<const float4*>(&wrp[k]);
            const float4 q0 = *reinterpret_cast<const float4*>(&x0p[k]);
            const float4 q1 = *reinterpret_cast<const float4*>(&x1p[k]);
            const float4 q2 = *reinterpret_cast<const float4*>(&x2p[k]);
            const float4 q3 = *reinterpret_cast<const float4*>(&x3p[k]);

            acc[0] = fmaf(wq.x, q0.x, acc[0]); acc[0] = fmaf(wq.y, q0.y, acc[0]);
            acc[0] = fmaf(wq.z, q0.z, acc[0]); acc[0] = fmaf(wq.w, q0.w, acc[0]);

            acc[1] = fmaf(wq.x, q1.x, acc[1]); acc[1] = fmaf(wq.y, q1.y, acc[1]);
            acc[1] = fmaf(wq.z, q1.z, acc[1]); acc[1] = fmaf(wq.w, q1.w, acc[1]);

            acc[2] = fmaf(wq.x, q2.x, acc[2]); acc[2] = fmaf(wq.y, q2.y, acc[2]);
            acc[2] = fmaf(wq.z, q2.z, acc[2]); acc[2] = fmaf(wq.w, q2.w, acc[2]);

            acc[3] = fmaf(wq.x, q3.x, acc[3]); acc[3] = fmaf(wq.y, q3.y, acc[3]);
            acc[3] = fmaf(wq.z, q3.z, acc[3]); acc[3] = fmaf(wq.w, q3.w, acc[3]);
        }
    }

    // ---- per-token top-3 across 64 lanes (stable: min index on ties) ----
    #pragma unroll
    for (int j = 0; j < 4; ++j) {
        float v = acc[j]; int bi = e;
        #pragma unroll
        for (int off = 32; off > 0; off >>= 1) {
            float ov = __shfl_xor(v, off);
            int   oi = __shfl_xor(bi, off);
            if (ov > v || (ov == v && oi < bi)) { v = ov; bi = oi; }
        }
        const float m1 = v; const int i1 = bi;

        float v2 = (e == i1) ? NEGF : acc[j]; int b2 = e;
        #pragma unroll
        for (int off = 32; off > 0; off >>= 1) {
            float ov = __shfl_xor(v2, off);
            int   oi = __shfl_xor(b2, off);
            if (ov > v2 || (ov == v2 && oi < b2)) { v2 = ov; b2 = oi; }
        }
        const float m2 = v2; const int i2 = b2;

        float v3 = (e == i1 || e == i2) ? NEGF : acc[j];
        #pragma unroll
        for (int off = 32; off > 0; off >>= 1) {
            float ov = __shfl_xor(v3, off);
            v3 = (ov > v3) ? ov : v3;
        }
        const float m3 = v3;

        if (e == 0) {
            const float r  = expf(m2 - m1);      // <= 1
            const float s  = 1.0f + r;
            const int   t  = t0 + g4 + j;
            out[2 * t + 0]        = (float)i1;
            out[2 * t + 1]        = (float)i2;
            out[woff + 2 * t + 0] = 1.0f / s;
            out[woff + 2 * t + 1] = r / s;
            flags[t] = ((m1 - m2 < TAU) || (m2 - m3 < TAU)) ? 1 : 0;
        }
    }
}

// ---------------- Pass 2: fp64 refine for flagged tokens --------------------
__global__ __launch_bounds__(64) void moe_refine_fp64(
    const float* __restrict__ x, const float* __restrict__ w,
    float* __restrict__ out, int woff,
    const unsigned char* __restrict__ flags, int T)
{
    const int e = threadIdx.x;
    for (int t = blockIdx.x; t < T; t += gridDim.x) {
        if (flags[t] == 0) continue;

        double acc = 0.0;
        const float* wr = &w[(size_t)e * H];
        const float* xr = &x[(size_t)t * H];
        for (int k = 0; k < H; k += 4) {
            const float4 wq = *reinterpret_cast<const float4*>(&wr[k]);
            const float4 xq = *reinterpret_cast<const float4*>(&xr[k]);
            acc = fma((double)wq.x, (double)xq.x, acc);
            acc = fma((double)wq.y, (double)xq.y, acc);
            acc = fma((double)wq.z, (double)xq.z, acc);
            acc = fma((double)wq.w, (double)xq.w, acc);
        }

        double v = acc; int bi = e;
        #pragma unroll
        for (int off = 32; off > 0; off >>= 1) {
            double ov = __shfl_xor(v, off);
            int    oi = __shfl_xor(bi, off);
            if (ov > v || (ov == v && oi < bi)) { v = ov; bi = oi; }
        }
        const double m1 = v; const int i1 = bi;

        double v2 = (e == i1) ? -1.0e300 : acc; int b2 = e;
        #pragma unroll
        for (int off = 32; off > 0; off >>= 1) {
            double ov = __shfl_xor(v2, off);
            int    oi = __shfl_xor(b2, off);
            if (ov > v2 || (ov == v2 && oi < b2)) { v2 = ov; b2 = oi; }
        }
        const double m2 = v2; const int i2 = b2;

        if (e == 0) {
            const double r = exp(m2 - m1);
            const double s = 1.0 + r;
            out[2 * t + 0]        = (float)i1;
            out[2 * t + 1]        = (float)i2;
            out[woff + 2 * t + 0] = (float)(1.0 / s);
            out[woff + 2 * t + 1] = (float)(r / s);
        }
    }
}

extern "C" void kernel_launch(void* const* d_in, const int* in_sizes, int n_in,
                              void* d_out, int out_size, void* d_ws, size_t ws_size,
                              hipStream_t stream) {
    const float* x   = (const float*)d_in[0];
    const float* wgt = (const float*)d_in[1];
    float* out = (float*)d_out;

    const int T    = in_sizes[0] / H;   // 16384
    const int woff = out_size / 2;      // 32768
    unsigned char* flags = (unsigned char*)d_ws;  // [T] bytes, fully rewritten each call

    moe_gate_fp32<<<dim3(T / TOKS), dim3(TPB), 0, stream>>>(x, wgt, out, woff, flags);
    moe_refine_fp64<<<dim3(512), dim3(64), 0, stream>>>(x, wgt, out, woff, flags, T);
}